// Round 1
// baseline (146.426 us; speedup 1.0000x reference)
//
#include <hip/hip_runtime.h>

#define EN 2048
#define SN 256
#define QN 25
#define NNODES 36
#define RN 15
#define HN 128
#define KP 96          // K=72 zero-padded to 96 for 3x k32 MFMA steps
#define NTOT (SN * RN) // 3840

typedef __attribute__((ext_vector_type(8))) short short8;
typedef __attribute__((ext_vector_type(4))) float f32x4;
typedef __attribute__((ext_vector_type(2))) unsigned int uint2v;

__device__ __forceinline__ unsigned short f2bf(float f) {
    unsigned int u = __float_as_uint(f);
    u += 0x7fffu + ((u >> 16) & 1u);   // round-to-nearest-even
    return (unsigned short)(u >> 16);
}
__device__ __forceinline__ float bf2f(unsigned short h) {
    return __uint_as_float(((unsigned int)h) << 16);
}
// tanh(x) = 1 - 2/(exp2(2x*log2e)+1); no clamp needed: exp2->inf gives rcp->0
// (tanh->1), exp2->0 gives rcp(1)=1 (tanh->-1). Saves 2 VALU ops per tanh.
__device__ __forceinline__ float fast_tanh(float x) {
    float e = __builtin_amdgcn_exp2f(x * 2.885390082f);
    float r = __builtin_amdgcn_rcpf(e + 1.f);
    return fmaf(-2.f, r, 1.f);
}

// ---------------- MLP helpers (validated R1-R3) ----------------------------
__device__ __forceinline__ void load_W(const float* __restrict__ W,
                                       unsigned short (*Ws)[136], int t)
{
    const int n = t & 127;
    const int h = t >> 7;
    #pragma unroll
    for (int kk = 0; kk < 16; kk++) {
        const int k0 = (kk * 2 + h) * 4;
        const float a0 = W[(k0 + 0) * HN + n];
        const float a1 = W[(k0 + 1) * HN + n];
        const float a2 = W[(k0 + 2) * HN + n];
        const float a3 = W[(k0 + 3) * HN + n];
        uint2v pk;
        pk[0] = (unsigned)f2bf(a0) | ((unsigned)f2bf(a1) << 16);
        pk[1] = (unsigned)f2bf(a2) | ((unsigned)f2bf(a3) << 16);
        *(uint2v*)&Ws[n][k0] = pk;
    }
}

__device__ __forceinline__ void mfma_layer(unsigned short (*Hs)[136],
                                           const unsigned short (*Ws)[136],
                                           const float* __restrict__ bias,
                                           int wv, int rowA, int quad)
{
    const int r0 = wv * 32;               // wave owns 32 rows: no barriers needed
    short8 afrag[2][4];
    #pragma unroll
    for (int rt = 0; rt < 2; rt++)
        #pragma unroll
        for (int kt = 0; kt < 4; kt++)
            afrag[rt][kt] = *(const short8*)&Hs[r0 + rt * 16 + rowA][kt * 32 + quad * 8];

    f32x4 acc[2][8];
    const f32x4 zero = {0.f, 0.f, 0.f, 0.f};
    #pragma unroll
    for (int rt = 0; rt < 2; rt++)
        #pragma unroll
        for (int nt = 0; nt < 8; nt++) acc[rt][nt] = zero;

    #pragma unroll
    for (int nt = 0; nt < 8; nt++) {
        #pragma unroll
        for (int kt = 0; kt < 4; kt++) {
            const short8 bfrag = *(const short8*)&Ws[nt * 16 + rowA][kt * 32 + quad * 8];
            acc[0][nt] = __builtin_amdgcn_mfma_f32_16x16x32_bf16(afrag[0][kt], bfrag, acc[0][nt], 0, 0, 0);
            acc[1][nt] = __builtin_amdgcn_mfma_f32_16x16x32_bf16(afrag[1][kt], bfrag, acc[1][nt], 0, 0, 0);
        }
    }
    #pragma unroll
    for (int nt = 0; nt < 8; nt++) {
        const int col = nt * 16 + rowA;
        const float bv = bias[col];
        #pragma unroll
        for (int rt = 0; rt < 2; rt++) {
            #pragma unroll
            for (int rg = 0; rg < 4; rg++) {
                const float v = fast_tanh(acc[rt][nt][rg] + bv);
                Hs[r0 + rt * 16 + quad * 4 + rg][col] = f2bf(v);
            }
        }
    }
}

// ---------------- fused prep: out-zero + Mcb(bf16, LDS-staged) + MLP -------
// Work ordering: light Mcb blocks FIRST (bid 0..255) so they vacate resident
// slots early and the 576 heavy MLP blocks backfill work-conservingly
// (576 units over 512 slots; MLP-first ordering forced a full 2nd round).
#define MC_BLOCKS  SN    // one block per sub-element s, bid 0..255
#define MLP_BLOCKS 576   // bid 256..831

__global__ __launch_bounds__(256, 2)
void prep_kernel(const float* __restrict__ nodes,
                 const float* __restrict__ W1, const float* __restrict__ b1,
                 const float* __restrict__ W2, const float* __restrict__ b2,
                 const float* __restrict__ W3, const float* __restrict__ b3,
                 const float* __restrict__ W4, const float* __restrict__ b4,
                 const float* __restrict__ B_DD,
                 const float* __restrict__ Ixx, const float* __restrict__ Iyy,
                 const float* __restrict__ wq, const float* __restrict__ Base,
                 const float* __restrict__ Fin, const float* __restrict__ Jin,
                 unsigned short* __restrict__ evcb,
                 unsigned short* __restrict__ Mcb,
                 float* __restrict__ out)
{
    __shared__ unsigned short Hs[128][136];
    __shared__ unsigned short Ws[128][136];
    __shared__ float WB[QN * 16];
    const int bid = blockIdx.x;
    const int t   = threadIdx.x;

    if (bid >= MC_BLOCKS) {
        // =========================== MLP part ===========================
        const int mb   = bid - MC_BLOCKS;
        const int lane = t & 63;
        const int wv   = t >> 6;
        const int rowA = lane & 15;
        const int quad = lane >> 4;

        // layer 1
        {
            const int p  = t >> 1;
            const int P  = mb * 128 + p;
            const float x0 = nodes[2 * P], x1 = nodes[2 * P + 1];
            const int n0 = (t & 1) * 64;
            #pragma unroll
            for (int i = 0; i < 16; i++) {
                const int n = n0 + 4 * i;
                const float4 wa = *(const float4*)(W1 + n);
                const float4 wb = *(const float4*)(W1 + HN + n);
                const float4 bb = *(const float4*)(b1 + n);
                const float h0 = fast_tanh(fmaf(x0, wa.x, fmaf(x1, wb.x, bb.x)));
                const float h1 = fast_tanh(fmaf(x0, wa.y, fmaf(x1, wb.y, bb.y)));
                const float h2 = fast_tanh(fmaf(x0, wa.z, fmaf(x1, wb.z, bb.z)));
                const float h3 = fast_tanh(fmaf(x0, wa.w, fmaf(x1, wb.w, bb.w)));
                uint2v pk;
                pk[0] = (unsigned)f2bf(h0) | ((unsigned)f2bf(h1) << 16);
                pk[1] = (unsigned)f2bf(h2) | ((unsigned)f2bf(h3) << 16);
                *(uint2v*)&Hs[p][n] = pk;
            }
        }
        load_W(W2, Ws, t);
        __syncthreads();
        mfma_layer(Hs, Ws, b2, wv, rowA, quad);
        __syncthreads();
        load_W(W3, Ws, t);
        __syncthreads();
        mfma_layer(Hs, Ws, b3, wv, rowA, quad);
        // layer 4 + evcb epilogue (bf16, K-padded)
        {
            const int p  = t >> 1;
            const int k0 = (t & 1) * 64;
            float d = 0.f;
            #pragma unroll
            for (int i = 0; i < 8; i++) {
                const short8 h = *(const short8*)&Hs[p][k0 + 8 * i];
                const float4 wA = *(const float4*)(W4 + k0 + 8 * i);
                const float4 wB = *(const float4*)(W4 + k0 + 8 * i + 4);
                d = fmaf(bf2f((unsigned short)h[0]), wA.x, d);
                d = fmaf(bf2f((unsigned short)h[1]), wA.y, d);
                d = fmaf(bf2f((unsigned short)h[2]), wA.z, d);
                d = fmaf(bf2f((unsigned short)h[3]), wA.w, d);
                d = fmaf(bf2f((unsigned short)h[4]), wB.x, d);
                d = fmaf(bf2f((unsigned short)h[5]), wB.y, d);
                d = fmaf(bf2f((unsigned short)h[6]), wB.z, d);
                d = fmaf(bf2f((unsigned short)h[7]), wB.w, d);
            }
            d += __shfl_xor(d, 1, 64);
            if ((t & 1) == 0) {
                const float ev = d + b4[0];
                const int P  = mb * 128 + p;
                const int e  = P / NNODES;
                const int ne = P - e * NNODES;
                const float c0 = B_DD[4 * e + 0] + B_DD[4 * e + 2];
                const float c1 = B_DD[4 * e + 1] + B_DD[4 * e + 3];
                evcb[e * KP + ne]          = f2bf(c0 * ev);
                evcb[e * KP + NNODES + ne] = f2bf(c1 * ev);
                if (ne < KP - 2 * NNODES)              // zero the 24-pad
                    evcb[e * KP + 2 * NNODES + ne] = 0;
            }
        }
    } else {
        // ============== Mcb part: one block per s, LDS-staged ===========
        const int s = bid;                        // 0..255
        if (s == 0 && t == 0) out[0] = 0.f;
        float* I_lds = (float*)&Hs[0][0];         // 1800 f32, aliases Hs
        for (int i = t; i < QN * 16; i += 256) {
            const int q = i >> 4, r = i & 15;
            if (r < RN) WB[i] = wq[q] * Base[q * RN + r];
        }
        const float* __restrict__ Ia = Ixx + (size_t)s * (QN * NNODES);
        const float* __restrict__ Ib = Iyy + (size_t)s * (QN * NNODES);
        for (int i = t; i < QN * NNODES; i += 256) {
            I_lds[i]               = Ia[i];
            I_lds[QN * NNODES + i] = Ib[i];
        }
        __syncthreads();
        // 15 r x 96 c outputs = 1440, 256 threads -> 6 strided iterations
        for (int o = t; o < RN * KP; o += 256) {
            const int c = o % KP;
            const int r = o / KP;
            float v = 0.f;
            if (c < 2 * NNODES) {
                const float* __restrict__ Ip =
                    I_lds + ((c < NNODES) ? c : (QN * NNODES + c - NNODES));
                float a0 = 0.f, a1 = 0.f;
                #pragma unroll
                for (int q = 0; q < QN - 1; q += 2) {
                    a0 = fmaf(WB[q * 16 + r],       Ip[q * NNODES],       a0);
                    a1 = fmaf(WB[(q + 1) * 16 + r], Ip[(q + 1) * NNODES], a1);
                }
                a0 = fmaf(WB[(QN - 1) * 16 + r], Ip[(QN - 1) * NNODES], a0);
                v = a0 + a1;
            }
            Mcb[((size_t)s * RN + r) * KP + c] = f2bf(v);
        }
        // ---- L3-warm F and J for loss_kernel -------------------------------
        // The 256MB workspace poison flushes L3 every iteration, so loss
        // re-reads F (31.5MB) cold from HBM. prep is VALU-bound with idle HBM:
        // stream F/J through here so loss hits the Infinity Cache instead.
        {
            const size_t base = (size_t)s * 256 + t;
            const size_t stride = (size_t)MC_BLOCKS * 256;
            const float4* F4 = (const float4*)Fin;
            const size_t nF4 = (size_t)EN * NTOT / 4;   // 1,966,080 -> 30/thread
            for (size_t i = base; i < nF4; i += stride) {
                float4 v = F4[i];
                asm volatile("" :: "v"(v.x), "v"(v.y), "v"(v.z), "v"(v.w));
            }
            const float4* J4 = (const float4*)Jin;
            const size_t nJ4 = (size_t)EN * SN / 4;     // 131,072 -> 2/thread
            for (size_t i = base; i < nJ4; i += stride) {
                float4 v = J4[i];
                asm volatile("" :: "v"(v.x), "v"(v.y), "v"(v.z), "v"(v.w));
            }
        }
    }
}

// ---------------- loss: bf16 MFMA GEMM + F-prefetch + fused epilogue -------
__global__ __launch_bounds__(256, 4)
void loss_kernel(const unsigned short* __restrict__ evcb,
                 const unsigned short* __restrict__ Mcb,
                 const float* __restrict__ J, const float* __restrict__ F,
                 float* __restrict__ out)
{
    const int t    = threadIdx.x;
    const int lane = t & 63;
    const int wv   = t >> 6;
    const int rowA = lane & 15;
    const int quad = lane >> 4;
    const int m0 = (blockIdx.x & 31) * 64;
    const int n0 = (blockIdx.x >> 5) * 128 + wv * 32;

    // prefetch F (the only HBM stream) before the GEMM: 32 loads in flight
    float Fv[2][16];
    #pragma unroll
    for (int nt = 0; nt < 2; nt++) {
        const int n = n0 + nt * 16 + rowA;
        #pragma unroll
        for (int mt = 0; mt < 4; mt++)
            #pragma unroll
            for (int rg = 0; rg < 4; rg++)
                Fv[nt][mt * 4 + rg] = F[(size_t)(m0 + mt * 16 + quad * 4 + rg) * NTOT + n];
    }

    f32x4 acc[4][2];
    const f32x4 zero = {0.f, 0.f, 0.f, 0.f};
    #pragma unroll
    for (int mt = 0; mt < 4; mt++)
        #pragma unroll
        for (int nt = 0; nt < 2; nt++) acc[mt][nt] = zero;

    #pragma unroll
    for (int kt = 0; kt < 3; kt++) {
        short8 a[4], b[2];
        #pragma unroll
        for (int mt = 0; mt < 4; mt++)
            a[mt] = *(const short8*)&evcb[(size_t)(m0 + mt * 16 + rowA) * KP + kt * 32 + quad * 8];
        #pragma unroll
        for (int nt = 0; nt < 2; nt++)
            b[nt] = *(const short8*)&Mcb[(size_t)(n0 + nt * 16 + rowA) * KP + kt * 32 + quad * 8];
        #pragma unroll
        for (int mt = 0; mt < 4; mt++)
            #pragma unroll
            for (int nt = 0; nt < 2; nt++)
                acc[mt][nt] = __builtin_amdgcn_mfma_f32_16x16x32_bf16(a[mt], b[nt], acc[mt][nt], 0, 0, 0);
    }

    // epilogue: res = -J*d - F; accumulate res^2/15 (flat sum == sum of means)
    float total = 0.f;
    #pragma unroll
    for (int nt = 0; nt < 2; nt++) {
        const int n = n0 + nt * 16 + rowA;
        const int s = (n * 34953) >> 19;               // n/15 for n<3840
        #pragma unroll
        for (int mt = 0; mt < 4; mt++) {
            const int eb = m0 + mt * 16 + quad * 4;
            #pragma unroll
            for (int rg = 0; rg < 4; rg++) {
                const float Jv = J[(size_t)(eb + rg) * SN + s];
                const float d  = acc[mt][nt][rg];
                const float res = fmaf(-Jv, d, -Fv[nt][mt * 4 + rg]);
                total = fmaf(res, res, total);
            }
        }
    }
    total *= (1.f / (float)RN);

    #pragma unroll
    for (int off = 32; off; off >>= 1)
        total += __shfl_down(total, off, 64);
    __shared__ float wsum[4];
    if (lane == 0) wsum[wv] = total;
    __syncthreads();
    if (t == 0) atomicAdd(out, (wsum[0] + wsum[1]) + (wsum[2] + wsum[3]));
}

extern "C" void kernel_launch(void* const* d_in, const int* in_sizes, int n_in,
                              void* d_out, int out_size, void* d_ws, size_t ws_size,
                              hipStream_t stream)
{
    (void)in_sizes; (void)n_in; (void)out_size; (void)ws_size;
    const float* nodes = (const float*)d_in[0];
    const float* W1   = (const float*)d_in[1];
    const float* b1   = (const float*)d_in[2];
    const float* W2   = (const float*)d_in[3];
    const float* b2   = (const float*)d_in[4];
    const float* W3   = (const float*)d_in[5];
    const float* b3   = (const float*)d_in[6];
    const float* W4   = (const float*)d_in[7];
    const float* b4   = (const float*)d_in[8];
    const float* Ixx  = (const float*)d_in[9];
    const float* Iyy  = (const float*)d_in[10];
    const float* B_DD = (const float*)d_in[11];
    const float* wq   = (const float*)d_in[12];
    const float* Base = (const float*)d_in[13];
    const float* J    = (const float*)d_in[14];
    const float* F    = (const float*)d_in[15];
    float* out = (float*)d_out;
    unsigned short* evcb = (unsigned short*)d_ws;                        // 2048*96 bf16
    unsigned short* Mcb  = (unsigned short*)((char*)d_ws + EN * KP * 2); // 3840*96 bf16

    prep_kernel<<<MC_BLOCKS + MLP_BLOCKS, 256, 0, stream>>>(
        nodes, W1, b1, W2, b2, W3, b3, W4, b4, B_DD, Ixx, Iyy, wq, Base,
        F, J, evcb, Mcb, out);
    loss_kernel<<<32 * 30, 256, 0, stream>>>(evcb, Mcb, J, F, out);
}

// Round 2
// 144.100 us; speedup vs baseline: 1.0161x; 1.0161x over previous
//
#include <hip/hip_runtime.h>

#define EN 2048
#define SN 256
#define QN 25
#define NNODES 36
#define RN 15
#define HN 128
#define KP 96          // K=72 zero-padded to 96 for 3x k32 MFMA steps
#define NTOT (SN * RN) // 3840

typedef __attribute__((ext_vector_type(8))) short short8;
typedef __attribute__((ext_vector_type(4))) float f32x4;
typedef __attribute__((ext_vector_type(2))) unsigned int uint2v;

__device__ __forceinline__ unsigned short f2bf(float f) {
    unsigned int u = __float_as_uint(f);
    u += 0x7fffu + ((u >> 16) & 1u);   // round-to-nearest-even
    return (unsigned short)(u >> 16);
}
__device__ __forceinline__ float bf2f(unsigned short h) {
    return __uint_as_float(((unsigned int)h) << 16);
}
// tanh(x) = 1 - 2/(exp2(2x*log2e)+1); exp2 saturation gives correct +-1 limits
__device__ __forceinline__ float fast_tanh(float x) {
    float e = __builtin_amdgcn_exp2f(x * 2.885390082f);
    float r = __builtin_amdgcn_rcpf(e + 1.f);
    return fmaf(-2.f, r, 1.f);
}

// ---------------- MLP helpers --------------------------------------------
// Stage ONE 64-column half of a 128x128 weight matrix (bf16, transposed to
// [col][k]) into Ws. Half-staging cuts LDS from 71.2KB to 53.8KB -> 3
// blocks/CU instead of 2 (the MLP is latency-bound at 2 waves/SIMD).
__device__ __forceinline__ void load_Wh(const float* __restrict__ W,
                                        unsigned short (*Wh)[136], int t, int half)
{
    const int n = t & 63;           // row within the 64-col half
    const int q = t >> 6;           // k-quarter 0..3
    const int col = half * 64 + n;
    #pragma unroll
    for (int i = 0; i < 8; i++) {
        const int k0 = q * 32 + i * 4;
        const float a0 = W[(k0 + 0) * HN + col];
        const float a1 = W[(k0 + 1) * HN + col];
        const float a2 = W[(k0 + 2) * HN + col];
        const float a3 = W[(k0 + 3) * HN + col];
        uint2v pk;
        pk[0] = (unsigned)f2bf(a0) | ((unsigned)f2bf(a1) << 16);
        pk[1] = (unsigned)f2bf(a2) | ((unsigned)f2bf(a3) << 16);
        *(uint2v*)&Wh[n][k0] = pk;
    }
}

// One nt-half (4 of 8 output col-tiles) of a 128x128 bf16 MFMA layer.
// afrag (the layer input, ALL k) is preloaded in registers by the caller, so
// epilogue writes to Hs cannot corrupt the A-operand of the second half.
__device__ __forceinline__ void mfma_half(unsigned short (*Hs)[136],
                                          const unsigned short (*Wh)[136],
                                          const float* __restrict__ bias,
                                          const short8 afrag[2][4],
                                          int r0, int rowA, int quad, int half)
{
    f32x4 acc[2][4];
    const f32x4 zero = {0.f, 0.f, 0.f, 0.f};
    #pragma unroll
    for (int rt = 0; rt < 2; rt++)
        #pragma unroll
        for (int nt = 0; nt < 4; nt++) acc[rt][nt] = zero;

    #pragma unroll
    for (int nt = 0; nt < 4; nt++) {
        #pragma unroll
        for (int kt = 0; kt < 4; kt++) {
            const short8 bfrag = *(const short8*)&Wh[nt * 16 + rowA][kt * 32 + quad * 8];
            acc[0][nt] = __builtin_amdgcn_mfma_f32_16x16x32_bf16(afrag[0][kt], bfrag, acc[0][nt], 0, 0, 0);
            acc[1][nt] = __builtin_amdgcn_mfma_f32_16x16x32_bf16(afrag[1][kt], bfrag, acc[1][nt], 0, 0, 0);
        }
    }
    #pragma unroll
    for (int nt = 0; nt < 4; nt++) {
        const int col = half * 64 + nt * 16 + rowA;
        const float bv = bias[col];
        #pragma unroll
        for (int rt = 0; rt < 2; rt++) {
            #pragma unroll
            for (int rg = 0; rg < 4; rg++) {
                const float v = fast_tanh(acc[rt][nt][rg] + bv);
                Hs[r0 + rt * 16 + quad * 4 + rg][col] = f2bf(v);
            }
        }
    }
}

// ---------------- fused prep: out-zero + Mcb(bf16, LDS-staged) + MLP -------
// Light Mcb blocks FIRST (bid 0..255) so they vacate resident slots early and
// the 576 heavy MLP blocks backfill work-conservingly.
#define MC_BLOCKS  SN    // one block per sub-element s, bid 0..255
#define MLP_BLOCKS 576   // bid 256..831

__global__ __launch_bounds__(256, 3)
void prep_kernel(const float* __restrict__ nodes,
                 const float* __restrict__ W1, const float* __restrict__ b1,
                 const float* __restrict__ W2, const float* __restrict__ b2,
                 const float* __restrict__ W3, const float* __restrict__ b3,
                 const float* __restrict__ W4, const float* __restrict__ b4,
                 const float* __restrict__ B_DD,
                 const float* __restrict__ Ixx, const float* __restrict__ Iyy,
                 const float* __restrict__ wq, const float* __restrict__ Base,
                 unsigned short* __restrict__ evcb,
                 unsigned short* __restrict__ Mcb,
                 float* __restrict__ out)
{
    __shared__ unsigned short Hs[128][136];   // 34,816 B
    __shared__ unsigned short Ws[64][136];    // 17,408 B (half-staged weights)
    __shared__ float WB[QN * 16];             //  1,600 B  -> 53.8 KB total
    const int bid = blockIdx.x;
    const int t   = threadIdx.x;

    if (bid >= MC_BLOCKS) {
        // =========================== MLP part ===========================
        const int mb   = bid - MC_BLOCKS;
        const int lane = t & 63;
        const int wv   = t >> 6;
        const int rowA = lane & 15;
        const int quad = lane >> 4;
        const int r0   = wv * 32;     // wave owns Hs rows r0..r0+31

        // layer 1
        {
            const int p  = t >> 1;
            const int P  = mb * 128 + p;
            const float x0 = nodes[2 * P], x1 = nodes[2 * P + 1];
            const int n0 = (t & 1) * 64;
            #pragma unroll
            for (int i = 0; i < 16; i++) {
                const int n = n0 + 4 * i;
                const float4 wa = *(const float4*)(W1 + n);
                const float4 wb = *(const float4*)(W1 + HN + n);
                const float4 bb = *(const float4*)(b1 + n);
                const float h0 = fast_tanh(fmaf(x0, wa.x, fmaf(x1, wb.x, bb.x)));
                const float h1 = fast_tanh(fmaf(x0, wa.y, fmaf(x1, wb.y, bb.y)));
                const float h2 = fast_tanh(fmaf(x0, wa.z, fmaf(x1, wb.z, bb.z)));
                const float h3 = fast_tanh(fmaf(x0, wa.w, fmaf(x1, wb.w, bb.w)));
                uint2v pk;
                pk[0] = (unsigned)f2bf(h0) | ((unsigned)f2bf(h1) << 16);
                pk[1] = (unsigned)f2bf(h2) | ((unsigned)f2bf(h3) << 16);
                *(uint2v*)&Hs[p][n] = pk;
            }
        }
        // ---- layer 2 (two Ws halves; afrag reg-held across both) ----
        short8 afrag[2][4];
        {
            load_Wh(W2, Ws, t, 0);
            #pragma unroll
            for (int rt = 0; rt < 2; rt++)
                #pragma unroll
                for (int kt = 0; kt < 4; kt++)
                    afrag[rt][kt] = *(const short8*)&Hs[r0 + rt * 16 + rowA][kt * 32 + quad * 8];
            __syncthreads();
            mfma_half(Hs, Ws, b2, afrag, r0, rowA, quad, 0);
            __syncthreads();
            load_Wh(W2, Ws, t, 1);
            __syncthreads();
            mfma_half(Hs, Ws, b2, afrag, r0, rowA, quad, 1);
            __syncthreads();            // protect Ws before W3 restage
        }
        // ---- layer 3 ----
        {
            load_Wh(W3, Ws, t, 0);
            #pragma unroll
            for (int rt = 0; rt < 2; rt++)
                #pragma unroll
                for (int kt = 0; kt < 4; kt++)
                    afrag[rt][kt] = *(const short8*)&Hs[r0 + rt * 16 + rowA][kt * 32 + quad * 8];
            __syncthreads();
            mfma_half(Hs, Ws, b3, afrag, r0, rowA, quad, 0);
            __syncthreads();
            load_Wh(W3, Ws, t, 1);
            __syncthreads();
            mfma_half(Hs, Ws, b3, afrag, r0, rowA, quad, 1);
        }
        // layer 4 + evcb epilogue (reads own-wave Hs rows; no barrier needed)
        {
            const int p  = t >> 1;
            const int k0 = (t & 1) * 64;
            float d = 0.f;
            #pragma unroll
            for (int i = 0; i < 8; i++) {
                const short8 h = *(const short8*)&Hs[p][k0 + 8 * i];
                const float4 wA = *(const float4*)(W4 + k0 + 8 * i);
                const float4 wB = *(const float4*)(W4 + k0 + 8 * i + 4);
                d = fmaf(bf2f((unsigned short)h[0]), wA.x, d);
                d = fmaf(bf2f((unsigned short)h[1]), wA.y, d);
                d = fmaf(bf2f((unsigned short)h[2]), wA.z, d);
                d = fmaf(bf2f((unsigned short)h[3]), wA.w, d);
                d = fmaf(bf2f((unsigned short)h[4]), wB.x, d);
                d = fmaf(bf2f((unsigned short)h[5]), wB.y, d);
                d = fmaf(bf2f((unsigned short)h[6]), wB.z, d);
                d = fmaf(bf2f((unsigned short)h[7]), wB.w, d);
            }
            d += __shfl_xor(d, 1, 64);
            if ((t & 1) == 0) {
                const float ev = d + b4[0];
                const int P  = mb * 128 + p;
                const int e  = P / NNODES;
                const int ne = P - e * NNODES;
                const float c0 = B_DD[4 * e + 0] + B_DD[4 * e + 2];
                const float c1 = B_DD[4 * e + 1] + B_DD[4 * e + 3];
                evcb[e * KP + ne]          = f2bf(c0 * ev);
                evcb[e * KP + NNODES + ne] = f2bf(c1 * ev);
                if (ne < KP - 2 * NNODES)              // zero the 24-pad
                    evcb[e * KP + 2 * NNODES + ne] = 0;
            }
        }
    } else {
        // ============== Mcb part: one block per s, LDS-staged ===========
        const int s = bid;                        // 0..255
        if (s == 0 && t == 0) out[0] = 0.f;
        float* I_lds = (float*)&Hs[0][0];         // 1800 f32, aliases Hs
        for (int i = t; i < QN * 16; i += 256) {
            const int q = i >> 4, r = i & 15;
            if (r < RN) WB[i] = wq[q] * Base[q * RN + r];
        }
        const float* __restrict__ Ia = Ixx + (size_t)s * (QN * NNODES);
        const float* __restrict__ Ib = Iyy + (size_t)s * (QN * NNODES);
        for (int i = t; i < QN * NNODES; i += 256) {
            I_lds[i]               = Ia[i];
            I_lds[QN * NNODES + i] = Ib[i];
        }
        __syncthreads();
        // 15 r x 96 c outputs = 1440, 256 threads -> 6 strided iterations
        for (int o = t; o < RN * KP; o += 256) {
            const int c = o % KP;
            const int r = o / KP;
            float v = 0.f;
            if (c < 2 * NNODES) {
                const float* __restrict__ Ip =
                    I_lds + ((c < NNODES) ? c : (QN * NNODES + c - NNODES));
                float a0 = 0.f, a1 = 0.f;
                #pragma unroll
                for (int q = 0; q < QN - 1; q += 2) {
                    a0 = fmaf(WB[q * 16 + r],       Ip[q * NNODES],       a0);
                    a1 = fmaf(WB[(q + 1) * 16 + r], Ip[(q + 1) * NNODES], a1);
                }
                a0 = fmaf(WB[(QN - 1) * 16 + r], Ip[(QN - 1) * NNODES], a0);
                v = a0 + a1;
            }
            Mcb[((size_t)s * RN + r) * KP + c] = f2bf(v);
        }
        // (R0's F/J L3-warm removed: measured neutral-at-best, cost ~5us of
        //  HBM streaming in these blocks.)
    }
}

// ---------------- loss: bf16 MFMA GEMM + F-prefetch + fused epilogue -------
__global__ __launch_bounds__(256, 4)
void loss_kernel(const unsigned short* __restrict__ evcb,
                 const unsigned short* __restrict__ Mcb,
                 const float* __restrict__ J, const float* __restrict__ F,
                 float* __restrict__ out)
{
    const int t    = threadIdx.x;
    const int lane = t & 63;
    const int wv   = t >> 6;
    const int rowA = lane & 15;
    const int quad = lane >> 4;
    const int m0 = (blockIdx.x & 31) * 64;
    const int n0 = (blockIdx.x >> 5) * 128 + wv * 32;

    // prefetch F (the only HBM stream) before the GEMM: 32 loads in flight
    float Fv[2][16];
    #pragma unroll
    for (int nt = 0; nt < 2; nt++) {
        const int n = n0 + nt * 16 + rowA;
        #pragma unroll
        for (int mt = 0; mt < 4; mt++)
            #pragma unroll
            for (int rg = 0; rg < 4; rg++)
                Fv[nt][mt * 4 + rg] = F[(size_t)(m0 + mt * 16 + quad * 4 + rg) * NTOT + n];
    }

    f32x4 acc[4][2];
    const f32x4 zero = {0.f, 0.f, 0.f, 0.f};
    #pragma unroll
    for (int mt = 0; mt < 4; mt++)
        #pragma unroll
        for (int nt = 0; nt < 2; nt++) acc[mt][nt] = zero;

    #pragma unroll
    for (int kt = 0; kt < 3; kt++) {
        short8 a[4], b[2];
        #pragma unroll
        for (int mt = 0; mt < 4; mt++)
            a[mt] = *(const short8*)&evcb[(size_t)(m0 + mt * 16 + rowA) * KP + kt * 32 + quad * 8];
        #pragma unroll
        for (int nt = 0; nt < 2; nt++)
            b[nt] = *(const short8*)&Mcb[(size_t)(n0 + nt * 16 + rowA) * KP + kt * 32 + quad * 8];
        #pragma unroll
        for (int mt = 0; mt < 4; mt++)
            #pragma unroll
            for (int nt = 0; nt < 2; nt++)
                acc[mt][nt] = __builtin_amdgcn_mfma_f32_16x16x32_bf16(a[mt], b[nt], acc[mt][nt], 0, 0, 0);
    }

    // epilogue: res = -J*d - F; accumulate res^2/15 (flat sum == sum of means)
    float total = 0.f;
    #pragma unroll
    for (int nt = 0; nt < 2; nt++) {
        const int n = n0 + nt * 16 + rowA;
        const int s = (n * 34953) >> 19;               // n/15 for n<3840
        #pragma unroll
        for (int mt = 0; mt < 4; mt++) {
            const int eb = m0 + mt * 16 + quad * 4;
            #pragma unroll
            for (int rg = 0; rg < 4; rg++) {
                const float Jv = J[(size_t)(eb + rg) * SN + s];
                const float d  = acc[mt][nt][rg];
                const float res = fmaf(-Jv, d, -Fv[nt][mt * 4 + rg]);
                total = fmaf(res, res, total);
            }
        }
    }
    total *= (1.f / (float)RN);

    #pragma unroll
    for (int off = 32; off; off >>= 1)
        total += __shfl_down(total, off, 64);
    __shared__ float wsum[4];
    if (lane == 0) wsum[wv] = total;
    __syncthreads();
    if (t == 0) atomicAdd(out, (wsum[0] + wsum[1]) + (wsum[2] + wsum[3]));
}

extern "C" void kernel_launch(void* const* d_in, const int* in_sizes, int n_in,
                              void* d_out, int out_size, void* d_ws, size_t ws_size,
                              hipStream_t stream)
{
    (void)in_sizes; (void)n_in; (void)out_size; (void)ws_size;
    const float* nodes = (const float*)d_in[0];
    const float* W1   = (const float*)d_in[1];
    const float* b1   = (const float*)d_in[2];
    const float* W2   = (const float*)d_in[3];
    const float* b2   = (const float*)d_in[4];
    const float* W3   = (const float*)d_in[5];
    const float* b3   = (const float*)d_in[6];
    const float* W4   = (const float*)d_in[7];
    const float* b4   = (const float*)d_in[8];
    const float* Ixx  = (const float*)d_in[9];
    const float* Iyy  = (const float*)d_in[10];
    const float* B_DD = (const float*)d_in[11];
    const float* wq   = (const float*)d_in[12];
    const float* Base = (const float*)d_in[13];
    const float* J    = (const float*)d_in[14];
    const float* F    = (const float*)d_in[15];
    float* out = (float*)d_out;
    unsigned short* evcb = (unsigned short*)d_ws;                        // 2048*96 bf16
    unsigned short* Mcb  = (unsigned short*)((char*)d_ws + EN * KP * 2); // 3840*96 bf16

    prep_kernel<<<MC_BLOCKS + MLP_BLOCKS, 256, 0, stream>>>(
        nodes, W1, b1, W2, b2, W3, b3, W4, b4, B_DD, Ixx, Iyy, wq, Base,
        evcb, Mcb, out);
    loss_kernel<<<32 * 30, 256, 0, stream>>>(evcb, Mcb, J, F, out);
}